// Round 11
// baseline (283.258 us; speedup 1.0000x reference)
//
#include <hip/hip_runtime.h>

// VectorQuantizer, 2-dispatch: norm+init, then fused gemm+argmax+epilogue.
//   wh = f16(16*w_hat), wl = f16(16*w_hat - wh)   (uniform x16: argmax-invariant)
//   zh = f16(4*z),      zl = f16(4*z - zh)        (uniform x4:  argmax-invariant)
//   dot64 = hh + hl + lh  (single f32 accumulator chain; ll ~2^-22 rel, dropped)
// argmin_k ||z_hat - w_hat_k|| == argmax_k <z, w_hat_k>  -> only codebook normalized.
//
// R10: finalize dispatch eliminated. Each (m,n) block atomicMax-publishes a
//   packed {fp32-key, ~idx} u64 per pixel; the 8th (last) finisher for an
//   m-tile decodes winners and writes indices + z_q (LDS-transpose in the
//   block's dead GEMM LDS), overlapped with other blocks' compute.

typedef _Float16 half8 __attribute__((ext_vector_type(8)));
typedef _Float16 half4 __attribute__((ext_vector_type(4)));
typedef float    floatx4 __attribute__((ext_vector_type(4)));

#define C_DIM 256
#define K_CODES 1024
#define HW 1024
#define NPIX 32768
#define NTILES 8          // n-tile blocks per pixel
#define USTR 520          // padded unit stride in f16 (512 data + 8 pad)

#define GLOAD_LDS16(g, l) __builtin_amdgcn_global_load_lds(                    \
    (const __attribute__((address_space(1))) unsigned int*)(g),                \
    (__attribute__((address_space(3))) unsigned int*)(l), 16, 0, 0)

// ---------------- kernel 1: normalize codebook + split + zero-init ----------
__global__ __launch_bounds__(256) void vq_norm_w(const float* __restrict__ w,
                                                 float* __restrict__ w_n,
                                                 _Float16* __restrict__ wh,
                                                 _Float16* __restrict__ wl,
                                                 unsigned long long* __restrict__ pack,
                                                 unsigned int* __restrict__ cnt) {
    const int row = blockIdx.x;        // 0..1023
    const int t   = threadIdx.x;       // 0..255
    const int gid = row * 256 + t;
    if (gid < NPIX) pack[gid] = 0ULL;  // < any real packed key
    if (gid < 256)  cnt[gid]  = 0u;
    float x = w[row * C_DIM + t];
    float s = x * x;
    #pragma unroll
    for (int off = 32; off > 0; off >>= 1) s += __shfl_down(s, off, 64);
    __shared__ float wsum[4];
    if ((t & 63) == 0) wsum[t >> 6] = s;
    __syncthreads();
    float tot = wsum[0] + wsum[1] + wsum[2] + wsum[3];
    float inv = 1.0f / fmaxf(sqrtf(tot), 1e-12f);
    float y = x * inv;
    w_n[row * C_DIM + t] = y;          // row-major: epilogue reads rows coalesced
    float ys = 16.0f * y;
    _Float16 hi = (_Float16)ys;
    wh[row * C_DIM + t] = hi;
    wl[row * C_DIM + t] = (_Float16)(ys - (float)hi);
}

// ---------------- kernel 2: fused split + MFMA GEMM + argmax + epilogue -----
// grid (256 m-tiles, 8 n-tiles), 256 thr = 4 waves 2x2; wave tile 64x64.
// BK=32, 8 phases (R6b-proven loop). Epilogue: packed atomicMax + last-block
// z_q write through reused LDS.
__global__ __launch_bounds__(256, 4) void vq_gemm(
        const float* __restrict__ z,
        const _Float16* __restrict__ wh, const _Float16* __restrict__ wl,
        const float* __restrict__ w_n,
        unsigned long long* __restrict__ pack,
        unsigned int* __restrict__ cnt,
        float* __restrict__ zq,          // [32][256][1024]
        float* __restrict__ idx_out) {   // [32768] as float
    __shared__ __align__(16) char smem[35328];
    _Float16* Ah = (_Float16*)smem;                    // 8*520*2 = 8320 B
    _Float16* Al = (_Float16*)(smem + 8320);
    _Float16* Bh = (_Float16*)(smem + 16640);
    _Float16* Bl = (_Float16*)(smem + 24960);
    float (*red_v)[2] = (float(*)[2])(smem + 33280);   // 1 KB
    int   (*red_i)[2] = (int  (*)[2])(smem + 34304);   // 1 KB
    float (*tile)[257] = (float(*)[257])smem;          // epilogue alias (32.9 KB)
    __shared__ int idx_s[128];
    __shared__ int lastflag;

    const int tid  = threadIdx.x;
    const int lane = tid & 63, wave = tid >> 6;
    const int wm = wave >> 1, wn = wave & 1;
    const int quad = lane >> 4, l15 = lane & 15;
    const int m0 = blockIdx.x * 128, n0 = blockIdx.y * 128;
    const int b  = m0 >> 10, p0 = m0 & 1023;

    // ---- B DMA setup: wave w stages 4 units; planes: w0,w1->Bh  w2,w3->Bl
    const _Float16* bsrc = (wave < 2) ? wh : wl;
    _Float16*       bdst = (wave < 2) ? Bh : Bl;
    const int ub = (wave & 1) * 4;
    const _Float16* gB[4];
    _Float16*       lB[4];
    #pragma unroll
    for (int i = 0; i < 4; i++) {
        gB[i] = bsrc + (size_t)(n0 + (ub + i) * 16 + l15) * C_DIM + quad * 8;
        lB[i] = bdst + (ub + i) * USTR;
    }

    // ---- A stage setup: wave = k-quad; lane -> (pixel group, k-subgroup)
    const int ap = (lane & 31) * 4;
    const int as = lane >> 5;
    const int ak = wave * 8 + as * 4;
    const float* zA = z + ((size_t)b * C_DIM + ak) * HW + p0 + ap;

    floatx4 acc[4][4];
    #pragma unroll
    for (int i = 0; i < 4; i++)
        #pragma unroll
        for (int j = 0; j < 4; j++) acc[i][j] = (floatx4){0.f, 0.f, 0.f, 0.f};

    const int afrag = wm * 4, bfrag = wn * 4;

    for (int kt = 0; kt < 8; kt++) {
        __syncthreads();
        #pragma unroll
        for (int i = 0; i < 4; i++)
            GLOAD_LDS16(gB[i] + kt * 32, lB[i]);
        floatx4 za[4];
        #pragma unroll
        for (int r = 0; r < 4; r++)
            za[r] = *(const floatx4*)(zA + (size_t)(kt * 32 + r) * HW);
        #pragma unroll
        for (int i = 0; i < 4; i++) {
            half4 hv, lv;
            #pragma unroll
            for (int r = 0; r < 4; r++) {
                float xv = 4.0f * za[r][i];
                _Float16 h = (_Float16)xv;
                hv[r] = h;
                lv[r] = (_Float16)(xv - (float)h);
            }
            const int p = ap + i;
            const int aidx = (p >> 4) * USTR + wave * 128 + (p & 15) * 8 + as * 4;
            *(half4*)&Ah[aidx] = hv;
            *(half4*)&Al[aidx] = lv;
        }
        __syncthreads();

        half8 ah[4], al[4], bh[4], bl[4];
        #pragma unroll
        for (int i = 0; i < 4; i++) {
            ah[i] = *(const half8*)&Ah[(afrag + i) * USTR + lane * 8];
            al[i] = *(const half8*)&Al[(afrag + i) * USTR + lane * 8];
            bh[i] = *(const half8*)&Bh[(bfrag + i) * USTR + lane * 8];
            bl[i] = *(const half8*)&Bl[(bfrag + i) * USTR + lane * 8];
        }
        #pragma unroll
        for (int mi = 0; mi < 4; mi++)
            #pragma unroll
            for (int ni = 0; ni < 4; ni++) {
                acc[mi][ni] = __builtin_amdgcn_mfma_f32_16x16x32_f16(ah[mi], bh[ni], acc[mi][ni], 0, 0, 0);
                acc[mi][ni] = __builtin_amdgcn_mfma_f32_16x16x32_f16(ah[mi], bl[ni], acc[mi][ni], 0, 0, 0);
                acc[mi][ni] = __builtin_amdgcn_mfma_f32_16x16x32_f16(al[mi], bh[ni], acc[mi][ni], 0, 0, 0);
            }
    }

    // ---- block-local argmax: per-lane best over ni, shfl over quad's 16 lanes
    #pragma unroll
    for (int mi = 0; mi < 4; mi++) {
        #pragma unroll
        for (int r = 0; r < 4; r++) {
            float bv = -__builtin_inff();
            int   bi = 0x7fffffff;
            #pragma unroll
            for (int ni = 0; ni < 4; ni++) {
                float v = acc[mi][ni][r];
                int  ci = n0 + wn * 64 + ni * 16 + l15;
                if (v > bv || (v == bv && ci < bi)) { bv = v; bi = ci; }
            }
            #pragma unroll
            for (int mk = 8; mk; mk >>= 1) {
                float ov = __shfl_xor(bv, mk, 16);
                int   oi = __shfl_xor(bi, mk, 16);
                if (ov > bv || (ov == bv && oi < bi)) { bv = ov; bi = oi; }
            }
            if (l15 == 0) {
                int row = wm * 64 + mi * 16 + quad * 4 + r;  // C/D: row=(lane>>4)*4+reg
                red_v[row][wn] = bv;
                red_i[row][wn] = bi;
            }
        }
    }
    __syncthreads();
    // ---- publish winners: packed {key, ~idx} atomicMax (tie -> smaller idx)
    if (tid < 128) {
        float bv = red_v[tid][0]; int bi = red_i[tid][0];
        float v2 = red_v[tid][1]; int i2 = red_i[tid][1];
        if (v2 > bv || (v2 == bv && i2 < bi)) { bv = v2; bi = i2; }
        unsigned bits = __float_as_uint(bv);
        unsigned key  = (bits & 0x80000000u) ? ~bits : (bits | 0x80000000u);
        unsigned long long pkd = ((unsigned long long)key << 32) | (unsigned)(~bi);
        atomicMax(&pack[m0 + tid], pkd);
    }
    __syncthreads();
    __threadfence();                               // release our atomics
    if (tid == 0) {
        unsigned old = atomicAdd(&cnt[blockIdx.x], 1u);
        lastflag = (old == NTILES - 1);
    }
    __syncthreads();
    if (!lastflag) return;

    // ---- LAST block for this m-tile: decode + write indices + z_q ----------
    __threadfence();                               // acquire others' atomics
    if (tid < 128) {
        unsigned long long pk = __hip_atomic_load(&pack[m0 + tid],
                                                  __ATOMIC_ACQUIRE,
                                                  __HIP_MEMORY_SCOPE_AGENT);
        int ci = (int)(~(unsigned)pk) & (K_CODES - 1);
        idx_s[tid] = ci;
        idx_out[m0 + tid] = (float)ci;
    }
    float* zqb = zq + (size_t)b * (C_DIM * HW) + p0;
    #pragma unroll
    for (int pass = 0; pass < 4; pass++) {
        __syncthreads();                           // tile reuse safe
        #pragma unroll
        for (int i = 0; i < 8; i++) {
            const int p = wave * 8 + i;            // 0..31
            const int row = idx_s[pass * 32 + p];
            floatx4 v = *(const floatx4*)(w_n + (size_t)row * C_DIM + lane * 4);
            *(floatx4*)&tile[p][lane * 4] = v;
        }
        __syncthreads();
        #pragma unroll
        for (int it = 0; it < 8; it++) {
            const int c  = it * 32 + (tid >> 3);   // 0..255
            const int p4 = (tid & 7) * 4;          // 0..28
            floatx4 v = { tile[p4][c], tile[p4 + 1][c], tile[p4 + 2][c], tile[p4 + 3][c] };
            *(floatx4*)(zqb + (size_t)c * HW + pass * 32 + p4) = v;
        }
    }
}

// ---------------- launcher --------------------------------------------------
extern "C" void kernel_launch(void* const* d_in, const int* in_sizes, int n_in,
                              void* d_out, int out_size, void* d_ws, size_t ws_size,
                              hipStream_t stream) {
    const float* z = (const float*)d_in[0];   // 32*256*32*32
    const float* w = (const float*)d_in[1];   // 1024*256
    float* out     = (float*)d_out;           // z_q (8388608) ++ indices (32768)

    char* ws = (char*)d_ws;
    float*    w_n  = (float*)(ws);                         //  0     .. 1 MB
    _Float16* wh   = (_Float16*)(ws + (1u << 20));         //  1 MB  .. 1.5 MB
    _Float16* wl   = (_Float16*)(ws + (3u << 19));         //  1.5   .. 2 MB
    unsigned long long* pack = (unsigned long long*)(ws + (2u << 20)); // 256 KB
    unsigned int*       cnt  = (unsigned int*)(ws + 2359296u);         // 1 KB

    vq_norm_w<<<K_CODES, 256, 0, stream>>>(w, w_n, wh, wl, pack, cnt);
    vq_gemm<<<dim3(NPIX / 128, NTILES), 256, 0, stream>>>(
        z, wh, wl, w_n, pack, cnt, out, out + 8388608);
}